// Round 1
// baseline (843.779 us; speedup 1.0000x reference)
//
#include <hip/hip_runtime.h>
#include <stdint.h>
#include <math.h>

// ---------------------------------------------------------------------------
// PathIntegration: h = relu(actions@w1+b1); trans = (h@w2+b2) -> [B,T,D,D]
// s_{t+1} = l2norm(relu(s_t @ trans_t)); output ys[B,T,D] (f32)
// B=32 T=512 A=64 H=256 D=128
// Phase 1: cast/transpose w2 -> w2t fp16 [N=16384][K=256]
// Phase 2: h fp16 [16384][256]
// Phase 3 (per T-chunk): fp16 MFMA GEMM -> trans chunk fp16 in ws
// Phase 4 (per T-chunk): 32 chains (1 block/batch) consume trans
// ---------------------------------------------------------------------------

typedef _Float16 f16x8 __attribute__((ext_vector_type(8)));
typedef _Float16 f16x2 __attribute__((ext_vector_type(2)));
typedef float    f32x4 __attribute__((ext_vector_type(4)));

#define B_  32
#define T_  512
#define A_  64
#define H_  256
#define D_  128
#define N_  (D_ * D_)      // 16384
#define M_  (B_ * T_)      // 16384

__device__ inline void async_ld16(const void* g, void* l) {
  __builtin_amdgcn_global_load_lds(
      (__attribute__((address_space(1))) void*)g,
      (__attribute__((address_space(3))) void*)l, 16, 0, 0);
}

// ---------------- w2 cast + transpose: [K=256][N=16384] f32 -> [N][K] fp16 ---
__global__ __launch_bounds__(256) void w2cast_kernel(const float* __restrict__ w2,
                                                     _Float16* __restrict__ w2t) {
  __shared__ float tile[64][65];
  const int t = threadIdx.x;
  const int n0 = blockIdx.x * 64, k0 = blockIdx.y * 64;
  const int nn = t & 63, kg = t >> 6;           // kg: 4 groups of 16 rows
  #pragma unroll
  for (int r = 0; r < 16; ++r) {
    int k = kg * 16 + r;
    tile[k][nn] = w2[(size_t)(k0 + k) * N_ + n0 + nn];
  }
  __syncthreads();
  const int kk = t & 63, ng = t >> 6;
  #pragma unroll
  for (int r = 0; r < 16; ++r) {
    int n = ng * 16 + r;
    w2t[(size_t)(n0 + n) * H_ + k0 + kk] = (_Float16)tile[kk][n];
  }
}

// ---------------- h = relu(actions@w1+b1) fp16 [16384][256] ------------------
__global__ __launch_bounds__(256) void h_kernel(const float* __restrict__ actions,
                                                const float* __restrict__ w1,
                                                const float* __restrict__ b1,
                                                _Float16* __restrict__ h16) {
  __shared__ float w1s[32 * 256];   // half of w1 at a time (32 KB)
  __shared__ float acts[32 * 64];   // 32 rows of actions (8 KB)
  const int t = threadIdx.x;        // column j = t
  const size_t row0 = (size_t)blockIdx.x * 32;

  #pragma unroll
  for (int i = 0; i < 8; ++i) acts[t + i * 256] = actions[row0 * A_ + t + i * 256];

  float acc[32];
  float bj = b1[t];
  #pragma unroll
  for (int r = 0; r < 32; ++r) acc[r] = bj;

  for (int half = 0; half < 2; ++half) {
    __syncthreads();
    #pragma unroll
    for (int i = 0; i < 32; ++i) w1s[t + i * 256] = w1[half * 32 * 256 + t + i * 256];
    __syncthreads();
    #pragma unroll
    for (int r = 0; r < 32; ++r) {
      float a = acc[r];
      #pragma unroll
      for (int k = 0; k < 32; ++k)
        a += acts[r * 64 + half * 32 + k] * w1s[k * 256 + t];
      acc[r] = a;
    }
  }
  #pragma unroll
  for (int r = 0; r < 32; ++r)
    h16[(row0 + r) * H_ + t] = (_Float16)fmaxf(acc[r], 0.f);
}

// ---------------- init s0 = l2norm(init_structure) broadcast [32][128] -------
__global__ void init_kernel(const float* __restrict__ init_s, float* __restrict__ s_ws) {
  const int t = threadIdx.x;  // 128 threads
  float x = init_s[t];
  float ss = x * x;
  #pragma unroll
  for (int off = 32; off > 0; off >>= 1) ss += __shfl_xor(ss, off);
  __shared__ float r2[2];
  if ((t & 63) == 0) r2[t >> 6] = ss;
  __syncthreads();
  float tot = r2[0] + r2[1];
  float s0 = x / fmaxf(sqrtf(tot), 1e-12f);
  for (int b = 0; b < B_; ++b) s_ws[b * D_ + t] = s0;
}

// ---------------- GEMM: trans_chunk[mc][n] = h[grow]@w2t[n] + b2[n] ----------
// BM=128 BN=128 BK=32, 4 waves each 64x64 (4x4 of 16x16x32 f16 MFMA). m97 recipe.
__global__ __launch_bounds__(256) void gemm_kernel(const _Float16* __restrict__ h16,
                                                   const _Float16* __restrict__ w2t,
                                                   const float* __restrict__ b2,
                                                   _Float16* __restrict__ trans,
                                                   int Tc, int t0) {
  __shared__ __align__(16) _Float16 smA[128 * 32];
  __shared__ __align__(16) _Float16 smB[128 * 32];
  const int tid  = threadIdx.x;
  const int lane = tid & 63;
  const int w    = tid >> 6;
  const int bm = blockIdx.y, bn = blockIdx.x;

  // staging: 512 16B-chunks per tile; chunk c -> row=c>>2, kchunk=c&3
  const int c0 = w * 64 + lane;
  const int c1 = 256 + c0;
  const int rA0 = c0 >> 2, kc0 = c0 & 3;
  const int rA1 = c1 >> 2, kc1 = c1 & 3;
  // A rows -> h global rows (decode chunk-local mc -> (b,tt))
  const int mc0 = bm * 128 + rA0, mc1 = bm * 128 + rA1;
  const int bb0 = mc0 / Tc, bb1 = mc1 / Tc;
  const long gr0 = (long)bb0 * T_ + t0 + (mc0 - bb0 * Tc);
  const long gr1 = (long)bb1 * T_ + t0 + (mc1 - bb1 * Tc);
  const _Float16* gA0 = h16 + gr0 * H_ + kc0 * 8;
  const _Float16* gA1 = h16 + gr1 * H_ + kc1 * 8;
  const _Float16* gB0 = w2t + (long)(bn * 128 + rA0) * H_ + kc0 * 8;
  const _Float16* gB1 = w2t + (long)(bn * 128 + rA1) * H_ + kc1 * 8;
  _Float16* lA0 = &smA[(w * 64) * 8];
  _Float16* lA1 = &smA[(256 + w * 64) * 8];
  _Float16* lB0 = &smB[(w * 64) * 8];
  _Float16* lB1 = &smB[(256 + w * 64) * 8];

  const int wm = w >> 1, wn = w & 1;
  const int fm = lane & 15, fq = lane >> 4;

  f32x4 zero = {0.f, 0.f, 0.f, 0.f};
  f32x4 acc[4][4];
  #pragma unroll
  for (int i = 0; i < 4; ++i)
    #pragma unroll
    for (int j = 0; j < 4; ++j) acc[i][j] = zero;

  for (int kt = 0; kt < H_ / 32; ++kt) {
    __syncthreads();
    async_ld16(gA0 + kt * 32, lA0);
    async_ld16(gA1 + kt * 32, lA1);
    async_ld16(gB0 + kt * 32, lB0);
    async_ld16(gB1 + kt * 32, lB1);
    __syncthreads();   // compiler drains vmcnt(0) before s_barrier
    f16x8 af[4], bf[4];
    #pragma unroll
    for (int mt = 0; mt < 4; ++mt)
      af[mt] = *(const f16x8*)&smA[(wm * 64 + mt * 16 + fm) * 32 + fq * 8];
    #pragma unroll
    for (int nt = 0; nt < 4; ++nt)
      bf[nt] = *(const f16x8*)&smB[(wn * 64 + nt * 16 + fm) * 32 + fq * 8];
    #pragma unroll
    for (int mt = 0; mt < 4; ++mt)
      #pragma unroll
      for (int nt = 0; nt < 4; ++nt)
        acc[mt][nt] = __builtin_amdgcn_mfma_f32_16x16x32_f16(af[mt], bf[nt], acc[mt][nt], 0, 0, 0);
  }

  // epilogue: C/D layout col=lane&15, row=(lane>>4)*4+r (m89/m91-verified)
  #pragma unroll
  for (int nt = 0; nt < 4; ++nt) {
    int col = bn * 128 + wn * 64 + nt * 16 + fm;
    float bias = b2[col];
    #pragma unroll
    for (int mt = 0; mt < 4; ++mt) {
      #pragma unroll
      for (int r = 0; r < 4; ++r) {
        long row = bm * 128 + wm * 64 + mt * 16 + fq * 4 + r;
        trans[row * (long)N_ + col] = (_Float16)(acc[mt][nt][r] + bias);
      }
    }
  }
}

// ---------------- recurrence: 1 block per batch, 512 threads -----------------
__global__ __launch_bounds__(512) void rec_kernel(const _Float16* __restrict__ trans,
                                                  float* __restrict__ s_ws,
                                                  float* __restrict__ out,
                                                  int Tc, int t0) {
  const int b = blockIdx.x;
  const int t = threadIdx.x;
  const int lane = t & 63;
  const int w = t >> 6;                   // i-group 0..7 (rows w*16..w*16+15)
  __shared__ float s_sh[128];
  __shared__ float2 partv[8][64];
  __shared__ float red[2];
  if (t < 128) s_sh[t] = s_ws[b * D_ + t];
  __syncthreads();

  const _Float16* Tb = trans + (size_t)b * Tc * N_ + w * 2048 + 2 * lane;

  f16x2 bufA[16], bufB[16];
  auto load_step = [&](f16x2* buf, int tt) {
    const f16x2* p = (const f16x2*)(Tb + (size_t)tt * N_);
    #pragma unroll
    for (int r = 0; r < 16; ++r) buf[r] = p[r * 64];   // stride 128 f16
  };
  // LDS-only barrier: keeps global prefetch (vmcnt) in flight across the step
  auto ldsbar = [&]() {
    asm volatile("s_waitcnt lgkmcnt(0)" ::: "memory");
    __builtin_amdgcn_s_barrier();
  };
  auto step = [&](const f16x2* buf, int tt) {
    float a0 = 0.f, a1 = 0.f;
    #pragma unroll
    for (int r = 0; r < 16; ++r) {
      float si = s_sh[w * 16 + r];
      a0 += si * (float)buf[r].x;
      a1 += si * (float)buf[r].y;
    }
    partv[w][lane] = make_float2(a0, a1);
    ldsbar();
    float u = 0.f;
    if (t < 128) {
      const float* pf = (const float*)partv;
      float v = 0.f;
      #pragma unroll
      for (int g = 0; g < 8; ++g) v += pf[g * 128 + t];
      u = fmaxf(v, 0.f);
      float ss = u * u;
      #pragma unroll
      for (int off = 32; off > 0; off >>= 1) ss += __shfl_xor(ss, off);
      if (lane == 0) red[w] = ss;       // w in {0,1} here
    }
    ldsbar();
    float tot = red[0] + red[1];
    float inv = 1.f / fmaxf(sqrtf(tot), 1e-12f);
    if (t < 128) {
      float sj = u * inv;
      s_sh[t] = sj;
      out[((size_t)b * T_ + t0 + tt) * D_ + t] = sj;
    }
    ldsbar();
  };

  load_step(bufA, 0);
  for (int tt = 0; tt < Tc; tt += 2) {
    load_step(bufB, tt + 1);
    step(bufA, tt);
    if (tt + 2 < Tc) load_step(bufA, tt + 2);
    step(bufB, tt + 1);
  }
  if (t < 128) s_ws[b * D_ + t] = s_sh[t];
}

// ---------------------------------------------------------------------------
extern "C" void kernel_launch(void* const* d_in, const int* in_sizes, int n_in,
                              void* d_out, int out_size, void* d_ws, size_t ws_size,
                              hipStream_t stream) {
  const float* actions = (const float*)d_in[0];   // [32,512,64]
  const float* init_s  = (const float*)d_in[1];   // [128]
  const float* w1      = (const float*)d_in[2];   // [64,256]
  const float* b1      = (const float*)d_in[3];   // [256]
  const float* w2      = (const float*)d_in[4];   // [256,16384]
  const float* b2      = (const float*)d_in[5];   // [16384]
  float* out = (float*)d_out;                     // [32,512,128]

  uint8_t* ws = (uint8_t*)d_ws;
  _Float16* w2t = (_Float16*)ws;                          // 8 MB
  _Float16* h16 = (_Float16*)(ws + ((size_t)8 << 20));    // 8 MB
  float* s_ws   = (float*)(ws + ((size_t)16 << 20));      // 16 KB
  const size_t trans_off = ((size_t)16 << 20) + 65536;
  _Float16* trans = (_Float16*)(ws + trans_off);

  // pick largest T-chunk fitting the workspace (chunk = 32*Tc*16384 fp16)
  int Tc = 32;
  const int cands[4] = {512, 256, 128, 64};
  for (int i = 0; i < 4; ++i) {
    if (trans_off + (size_t)B_ * cands[i] * N_ * 2 <= ws_size) { Tc = cands[i]; break; }
  }

  w2cast_kernel<<<dim3(N_ / 64, 4), 256, 0, stream>>>(w2, w2t);
  h_kernel<<<M_ / 32, 256, 0, stream>>>(actions, w1, b1, h16);
  init_kernel<<<1, 128, 0, stream>>>(init_s, s_ws);

  const int nch = T_ / Tc;
  for (int c = 0; c < nch; ++c) {
    int t0 = c * Tc;
    int Mc = B_ * Tc;
    gemm_kernel<<<dim3(N_ / 128, Mc / 128), 256, 0, stream>>>(h16, w2t, b2, trans, Tc, t0);
    rec_kernel<<<B_, 512, 0, stream>>>(trans, s_ws, out, Tc, t0);
  }
}

// Round 2
// 801.795 us; speedup vs baseline: 1.0524x; 1.0524x over previous
//
#include <hip/hip_runtime.h>
#include <stdint.h>
#include <math.h>

// ---------------------------------------------------------------------------
// PathIntegration: h = relu(actions@w1+b1); trans = (h@w2+b2) -> [B,T,D,D]
// s_{t+1} = l2norm(relu(s_t @ trans_t)); output ys[B,T,D] (f32)
// B=32 T=512 A=64 H=256 D=128
// Phase 1: cast/transpose w2 -> w2t fp16 [N=16384][K=256]
// Phase 2: h fp16 [16384][256]
// Phase 3 (per T-chunk): fp16 MFMA GEMM -> trans chunk fp16 in ws
// Phase 4 (per T-chunk): 32 chains (1 block/batch), 16B loads, 4-deep
//         register prefetch, deferred-normalization (2 LDS barriers/step)
// ---------------------------------------------------------------------------

typedef _Float16 f16x8 __attribute__((ext_vector_type(8)));
typedef float    f32x4 __attribute__((ext_vector_type(4)));

#define B_  32
#define T_  512
#define A_  64
#define H_  256
#define D_  128
#define N_  (D_ * D_)      // 16384
#define M_  (B_ * T_)      // 16384

__device__ inline void async_ld16(const void* g, void* l) {
  __builtin_amdgcn_global_load_lds(
      (__attribute__((address_space(1))) void*)g,
      (__attribute__((address_space(3))) void*)l, 16, 0, 0);
}

// ---------------- w2 cast + transpose: [K=256][N=16384] f32 -> [N][K] fp16 ---
__global__ __launch_bounds__(256) void w2cast_kernel(const float* __restrict__ w2,
                                                     _Float16* __restrict__ w2t) {
  __shared__ float tile[64][65];
  const int t = threadIdx.x;
  const int n0 = blockIdx.x * 64, k0 = blockIdx.y * 64;
  const int nn = t & 63, kg = t >> 6;           // kg: 4 groups of 16 rows
  #pragma unroll
  for (int r = 0; r < 16; ++r) {
    int k = kg * 16 + r;
    tile[k][nn] = w2[(size_t)(k0 + k) * N_ + n0 + nn];
  }
  __syncthreads();
  const int kk = t & 63, ng = t >> 6;
  #pragma unroll
  for (int r = 0; r < 16; ++r) {
    int n = ng * 16 + r;
    w2t[(size_t)(n0 + n) * H_ + k0 + kk] = (_Float16)tile[kk][n];
  }
}

// ---------------- h = relu(actions@w1+b1) fp16 [16384][256] ------------------
__global__ __launch_bounds__(256) void h_kernel(const float* __restrict__ actions,
                                                const float* __restrict__ w1,
                                                const float* __restrict__ b1,
                                                _Float16* __restrict__ h16) {
  __shared__ float w1s[32 * 256];   // half of w1 at a time (32 KB)
  __shared__ float acts[32 * 64];   // 32 rows of actions (8 KB)
  const int t = threadIdx.x;        // column j = t
  const size_t row0 = (size_t)blockIdx.x * 32;

  #pragma unroll
  for (int i = 0; i < 8; ++i) acts[t + i * 256] = actions[row0 * A_ + t + i * 256];

  float acc[32];
  float bj = b1[t];
  #pragma unroll
  for (int r = 0; r < 32; ++r) acc[r] = bj;

  for (int half = 0; half < 2; ++half) {
    __syncthreads();
    #pragma unroll
    for (int i = 0; i < 32; ++i) w1s[t + i * 256] = w1[half * 32 * 256 + t + i * 256];
    __syncthreads();
    #pragma unroll
    for (int r = 0; r < 32; ++r) {
      float a = acc[r];
      #pragma unroll
      for (int k = 0; k < 32; ++k)
        a += acts[r * 64 + half * 32 + k] * w1s[k * 256 + t];
      acc[r] = a;
    }
  }
  #pragma unroll
  for (int r = 0; r < 32; ++r)
    h16[(row0 + r) * H_ + t] = (_Float16)fmaxf(acc[r], 0.f);
}

// ---------------- init s0 = l2norm(init_structure) broadcast [32][128] -------
__global__ void init_kernel(const float* __restrict__ init_s, float* __restrict__ s_ws) {
  const int t = threadIdx.x;  // 128 threads
  float x = init_s[t];
  float ss = x * x;
  #pragma unroll
  for (int off = 32; off > 0; off >>= 1) ss += __shfl_xor(ss, off);
  __shared__ float r2[2];
  if ((t & 63) == 0) r2[t >> 6] = ss;
  __syncthreads();
  float tot = r2[0] + r2[1];
  float s0 = x / fmaxf(sqrtf(tot), 1e-12f);
  for (int b = 0; b < B_; ++b) s_ws[b * D_ + t] = s0;
}

// ---------------- GEMM: trans_chunk[mc][n] = h[grow]@w2t[n] + b2[n] ----------
// BM=128 BN=128 BK=32, 4 waves each 64x64 (4x4 of 16x16x32 f16 MFMA). m97 recipe.
__global__ __launch_bounds__(256) void gemm_kernel(const _Float16* __restrict__ h16,
                                                   const _Float16* __restrict__ w2t,
                                                   const float* __restrict__ b2,
                                                   _Float16* __restrict__ trans,
                                                   int Tc, int t0) {
  __shared__ __align__(16) _Float16 smA[128 * 32];
  __shared__ __align__(16) _Float16 smB[128 * 32];
  const int tid  = threadIdx.x;
  const int lane = tid & 63;
  const int w    = tid >> 6;
  const int bm = blockIdx.y, bn = blockIdx.x;

  // staging: 512 16B-chunks per tile; chunk c -> row=c>>2, kchunk=c&3
  const int c0 = w * 64 + lane;
  const int c1 = 256 + c0;
  const int rA0 = c0 >> 2, kc0 = c0 & 3;
  const int rA1 = c1 >> 2, kc1 = c1 & 3;
  // A rows -> h global rows (decode chunk-local mc -> (b,tt))
  const int mc0 = bm * 128 + rA0, mc1 = bm * 128 + rA1;
  const int bb0 = mc0 / Tc, bb1 = mc1 / Tc;
  const long gr0 = (long)bb0 * T_ + t0 + (mc0 - bb0 * Tc);
  const long gr1 = (long)bb1 * T_ + t0 + (mc1 - bb1 * Tc);
  const _Float16* gA0 = h16 + gr0 * H_ + kc0 * 8;
  const _Float16* gA1 = h16 + gr1 * H_ + kc1 * 8;
  const _Float16* gB0 = w2t + (long)(bn * 128 + rA0) * H_ + kc0 * 8;
  const _Float16* gB1 = w2t + (long)(bn * 128 + rA1) * H_ + kc1 * 8;
  _Float16* lA0 = &smA[(w * 64) * 8];
  _Float16* lA1 = &smA[(256 + w * 64) * 8];
  _Float16* lB0 = &smB[(w * 64) * 8];
  _Float16* lB1 = &smB[(256 + w * 64) * 8];

  const int wm = w >> 1, wn = w & 1;
  const int fm = lane & 15, fq = lane >> 4;

  f32x4 zero = {0.f, 0.f, 0.f, 0.f};
  f32x4 acc[4][4];
  #pragma unroll
  for (int i = 0; i < 4; ++i)
    #pragma unroll
    for (int j = 0; j < 4; ++j) acc[i][j] = zero;

  for (int kt = 0; kt < H_ / 32; ++kt) {
    __syncthreads();
    async_ld16(gA0 + kt * 32, lA0);
    async_ld16(gA1 + kt * 32, lA1);
    async_ld16(gB0 + kt * 32, lB0);
    async_ld16(gB1 + kt * 32, lB1);
    __syncthreads();   // compiler drains vmcnt(0) before s_barrier
    f16x8 af[4], bf[4];
    #pragma unroll
    for (int mt = 0; mt < 4; ++mt)
      af[mt] = *(const f16x8*)&smA[(wm * 64 + mt * 16 + fm) * 32 + fq * 8];
    #pragma unroll
    for (int nt = 0; nt < 4; ++nt)
      bf[nt] = *(const f16x8*)&smB[(wn * 64 + nt * 16 + fm) * 32 + fq * 8];
    #pragma unroll
    for (int mt = 0; mt < 4; ++mt)
      #pragma unroll
      for (int nt = 0; nt < 4; ++nt)
        acc[mt][nt] = __builtin_amdgcn_mfma_f32_16x16x32_f16(af[mt], bf[nt], acc[mt][nt], 0, 0, 0);
  }

  // epilogue: C/D layout col=lane&15, row=(lane>>4)*4+r (m89/m91-verified)
  #pragma unroll
  for (int nt = 0; nt < 4; ++nt) {
    int col = bn * 128 + wn * 64 + nt * 16 + fm;
    float bias = b2[col];
    #pragma unroll
    for (int mt = 0; mt < 4; ++mt) {
      #pragma unroll
      for (int r = 0; r < 4; ++r) {
        long row = bm * 128 + wm * 64 + mt * 16 + fq * 4 + r;
        trans[row * (long)N_ + col] = (_Float16)(acc[mt][nt][r] + bias);
      }
    }
  }
}

// ---------------- recurrence: 1 block per batch, 512 threads -----------------
// Layout: thread t covers rows {k*32 + (t>>4)} (k=0..3), col-block jb=(t&15)*8.
// Each lane: 4x 16B loads/step (wave-instr = 4 contiguous rows, 1KB).
// 4-step register prefetch ring; deferred normalization: s_sh holds
// v_t / ||v_{t-1}|| (relu(ax)=a*relu(x), positive scale cancels in l2norm);
// ||v_t|| computed overlapped with step t+1's FMAs; output written 1 step late.
__global__ __launch_bounds__(512) void rec_kernel(const _Float16* __restrict__ trans,
                                                  float* __restrict__ s_ws,
                                                  float* __restrict__ out,
                                                  int Tc, int t0) {
  const int b = blockIdx.x;
  const int t = threadIdx.x;
  const int lane = t & 63;
  const int w = t >> 6;
  __shared__ float s_sh[128];
  __shared__ float partv[8][128];
  __shared__ float red2[8];   // only [0],[1] used

  float vprev = 0.f;
  if (t < 128) {
    float s0v = s_ws[b * D_ + t];
    s_sh[t] = s0v;
    vprev = s0v;              // norm 1 at chunk start -> step 0 inv = 1
  }
  __syncthreads();

  const _Float16* Tbase = trans + (size_t)b * Tc * N_ + (t >> 4) * 128 + (t & 15) * 8;

  // LDS-only barrier: keeps global prefetch (vmcnt) in flight across steps
  auto ldsbar = [&]() {
    asm volatile("s_waitcnt lgkmcnt(0)" ::: "memory");
    __builtin_amdgcn_s_barrier();
  };

  f16x8 buf[4][4];
  #pragma unroll
  for (int u = 0; u < 4; ++u) {
    const f16x8* p = (const f16x8*)(Tbase + (size_t)u * N_);
    #pragma unroll
    for (int k = 0; k < 4; ++k) buf[u][k] = p[k * 512];   // row stride 32*128 f16
  }

  for (int tt0 = 0; tt0 < Tc; tt0 += 4) {
    #pragma unroll
    for (int u = 0; u < 4; ++u) {
      const int tt = tt0 + u;
      float a[8];
      #pragma unroll
      for (int c = 0; c < 8; ++c) a[c] = 0.f;
      #pragma unroll
      for (int k = 0; k < 4; ++k) {
        float si = s_sh[k * 32 + (t >> 4)];
        #pragma unroll
        for (int c = 0; c < 8; ++c) a[c] += si * (float)buf[u][k][c];
      }
      // prefetch step tt+4 into the just-consumed registers
      if (tt + 4 < Tc) {
        const f16x8* p = (const f16x8*)(Tbase + (size_t)(tt + 4) * N_);
        #pragma unroll
        for (int k = 0; k < 4; ++k) buf[u][k] = p[k * 512];
      }
      // reduce partials over row-subgroups (lanes ^16, ^32 share jb)
      #pragma unroll
      for (int c = 0; c < 8; ++c) {
        a[c] += __shfl_xor(a[c], 16);
        a[c] += __shfl_xor(a[c], 32);
      }
      if (lane < 16) {
        #pragma unroll
        for (int c = 0; c < 8; ++c) partv[w][lane * 8 + c] = a[c];
      }
      // overlapped: ||v_prev||^2 (waves 0,1 only)
      if (t < 128) {
        float ss = vprev * vprev;
        #pragma unroll
        for (int off = 32; off > 0; off >>= 1) ss += __shfl_xor(ss, off);
        if (lane == 0) red2[w] = ss;
      }
      ldsbar();   // partv + red2 visible; everyone done reading s_sh
      if (t < 128) {
        float uj = 0.f;
        #pragma unroll
        for (int g = 0; g < 8; ++g) uj += partv[g][t];
        float v = fmaxf(uj, 0.f);
        float inv = 1.f / fmaxf(sqrtf(red2[0] + red2[1]), 1e-12f);
        if (tt > 0)
          out[((size_t)b * T_ + t0 + tt - 1) * D_ + t] = vprev * inv;
        s_sh[t] = v * inv;   // v_t / ||v_{t-1}|| — bounded, direction-exact
        vprev = v;
      }
      ldsbar();   // s_sh ready for next step
    }
  }

  // epilogue: final norm, last output, carry fully-normalized state
  if (t < 128) {
    float ss = vprev * vprev;
    #pragma unroll
    for (int off = 32; off > 0; off >>= 1) ss += __shfl_xor(ss, off);
    if (lane == 0) red2[w] = ss;
  }
  ldsbar();
  if (t < 128) {
    float inv = 1.f / fmaxf(sqrtf(red2[0] + red2[1]), 1e-12f);
    float sj = vprev * inv;
    out[((size_t)b * T_ + t0 + Tc - 1) * D_ + t] = sj;
    s_ws[b * D_ + t] = sj;
  }
}

// ---------------------------------------------------------------------------
extern "C" void kernel_launch(void* const* d_in, const int* in_sizes, int n_in,
                              void* d_out, int out_size, void* d_ws, size_t ws_size,
                              hipStream_t stream) {
  const float* actions = (const float*)d_in[0];   // [32,512,64]
  const float* init_s  = (const float*)d_in[1];   // [128]
  const float* w1      = (const float*)d_in[2];   // [64,256]
  const float* b1      = (const float*)d_in[3];   // [256]
  const float* w2      = (const float*)d_in[4];   // [256,16384]
  const float* b2      = (const float*)d_in[5];   // [16384]
  float* out = (float*)d_out;                     // [32,512,128]

  uint8_t* ws = (uint8_t*)d_ws;
  _Float16* w2t = (_Float16*)ws;                          // 8 MB
  _Float16* h16 = (_Float16*)(ws + ((size_t)8 << 20));    // 8 MB
  float* s_ws   = (float*)(ws + ((size_t)16 << 20));      // 16 KB
  const size_t trans_off = ((size_t)16 << 20) + 65536;
  _Float16* trans = (_Float16*)(ws + trans_off);

  // pick largest T-chunk fitting the workspace (chunk = 32*Tc*16384 fp16)
  int Tc = 32;
  const int cands[4] = {512, 256, 128, 64};
  for (int i = 0; i < 4; ++i) {
    if (trans_off + (size_t)B_ * cands[i] * N_ * 2 <= ws_size) { Tc = cands[i]; break; }
  }

  w2cast_kernel<<<dim3(N_ / 64, 4), 256, 0, stream>>>(w2, w2t);
  h_kernel<<<M_ / 32, 256, 0, stream>>>(actions, w1, b1, h16);
  init_kernel<<<1, 128, 0, stream>>>(init_s, s_ws);

  const int nch = T_ / Tc;
  for (int c = 0; c < nch; ++c) {
    int t0 = c * Tc;
    int Mc = B_ * Tc;
    gemm_kernel<<<dim3(N_ / 128, Mc / 128), 256, 0, stream>>>(h16, w2t, b2, trans, Tc, t0);
    rec_kernel<<<B_, 512, 0, stream>>>(trans, s_ws, out, Tc, t0);
  }
}

// Round 3
// 682.655 us; speedup vs baseline: 1.2360x; 1.1745x over previous
//
#include <hip/hip_runtime.h>
#include <stdint.h>
#include <math.h>

// ---------------------------------------------------------------------------
// PathIntegration: h = relu(actions@w1+b1); trans = (h@w2+b2) -> [B,T,D,D]
// s_{t+1} = l2norm(relu(s_t @ trans_t)); output ys[B,T,D] (f32)
// B=32 T=512 A=64 H=256 D=128
// Round 3: fused launches — blocks 0..31 run rec chunk c (critical path,
// ~32 CUs at per-CU streaming limit), blocks 32.. run GEMM chunk c+1 on the
// other ~224 CUs. trans double-buffered; state carried through out[t0-1].
// ---------------------------------------------------------------------------

typedef _Float16 f16x8 __attribute__((ext_vector_type(8)));
typedef float    f32x4 __attribute__((ext_vector_type(4)));

#define B_  32
#define T_  512
#define A_  64
#define H_  256
#define D_  128
#define N_  (D_ * D_)      // 16384
#define M_  (B_ * T_)      // 16384

__device__ inline void async_ld16(const void* g, void* l) {
  __builtin_amdgcn_global_load_lds(
      (__attribute__((address_space(1))) void*)g,
      (__attribute__((address_space(3))) void*)l, 16, 0, 0);
}

// ---------------- w2 cast + transpose: [K=256][N=16384] f32 -> [N][K] fp16 ---
__global__ __launch_bounds__(256) void w2cast_kernel(const float* __restrict__ w2,
                                                     _Float16* __restrict__ w2t) {
  __shared__ float tile[64][65];
  const int t = threadIdx.x;
  const int n0 = blockIdx.x * 64, k0 = blockIdx.y * 64;
  const int nn = t & 63, kg = t >> 6;
  #pragma unroll
  for (int r = 0; r < 16; ++r) {
    int k = kg * 16 + r;
    tile[k][nn] = w2[(size_t)(k0 + k) * N_ + n0 + nn];
  }
  __syncthreads();
  const int kk = t & 63, ng = t >> 6;
  #pragma unroll
  for (int r = 0; r < 16; ++r) {
    int n = ng * 16 + r;
    w2t[(size_t)(n0 + n) * H_ + k0 + kk] = (_Float16)tile[kk][n];
  }
}

// ---------------- h = relu(actions@w1+b1) fp16 [16384][256] ------------------
__global__ __launch_bounds__(256) void h_kernel(const float* __restrict__ actions,
                                                const float* __restrict__ w1,
                                                const float* __restrict__ b1,
                                                _Float16* __restrict__ h16) {
  __shared__ float w1s[32 * 256];
  __shared__ float acts[32 * 64];
  const int t = threadIdx.x;
  const size_t row0 = (size_t)blockIdx.x * 32;

  #pragma unroll
  for (int i = 0; i < 8; ++i) acts[t + i * 256] = actions[row0 * A_ + t + i * 256];

  float acc[32];
  float bj = b1[t];
  #pragma unroll
  for (int r = 0; r < 32; ++r) acc[r] = bj;

  for (int half = 0; half < 2; ++half) {
    __syncthreads();
    #pragma unroll
    for (int i = 0; i < 32; ++i) w1s[t + i * 256] = w1[half * 32 * 256 + t + i * 256];
    __syncthreads();
    #pragma unroll
    for (int r = 0; r < 32; ++r) {
      float a = acc[r];
      #pragma unroll
      for (int k = 0; k < 32; ++k)
        a += acts[r * 64 + half * 32 + k] * w1s[k * 256 + t];
      acc[r] = a;
    }
  }
  #pragma unroll
  for (int r = 0; r < 32; ++r)
    h16[(row0 + r) * H_ + t] = (_Float16)fmaxf(acc[r], 0.f);
}

// ---------------- fused: rec(chunk c) on blocks 0..31, gemm(chunk c+1) else --
__global__ __launch_bounds__(512) void fused_kernel(
    const _Float16* __restrict__ h16, const _Float16* __restrict__ w2t,
    const float* __restrict__ b2, _Float16* __restrict__ tbuf0,
    _Float16* __restrict__ tbuf1, const float* __restrict__ init_s,
    float* __restrict__ out, int Tc, int tcs, int c, int nch) {

  __shared__ __align__(16) char smem[16640];
  const int tid  = threadIdx.x;
  const int lane = tid & 63;
  const int w    = tid >> 6;

  if (blockIdx.x < 32) {
    // ======================= recurrence block ===============================
    if (c < 0) return;
    const _Float16* trans = (c & 1) ? tbuf1 : tbuf0;
    const int b  = blockIdx.x;
    const int t0 = c * Tc;
    const int t  = tid;

    float* s_sh  = (float*)smem;             // 128 f32
    float* partv = (float*)(smem + 512);     // [8][128] f32
    float* red2  = (float*)(smem + 4608);    // 8 f32 (only [0],[1] used)

    auto ldsbar = [&]() {
      asm volatile("s_waitcnt lgkmcnt(0)" ::: "memory");
      __builtin_amdgcn_s_barrier();
    };

    // load/init state; normalize (idempotent for already-unit carry state)
    float vprev = 0.f;
    if (t < 128) {
      float s0v = (t0 == 0) ? init_s[t] : out[((size_t)b * T_ + t0 - 1) * D_ + t];
      float ss = s0v * s0v;
      #pragma unroll
      for (int off = 32; off > 0; off >>= 1) ss += __shfl_xor(ss, off);
      if (lane == 0) red2[w] = ss;
      vprev = s0v;
    }
    ldsbar();
    if (t < 128) {
      float inv = 1.f / fmaxf(sqrtf(red2[0] + red2[1]), 1e-12f);
      float sv = vprev * inv;
      s_sh[t] = sv;
      vprev = sv;        // unit norm -> step-0 deferred inv = 1
    }
    ldsbar();

    const _Float16* Tbase = trans + (size_t)b * Tc * N_ + (t >> 4) * 128 + (t & 15) * 8;

    f16x8 buf[4][4];
    #pragma unroll
    for (int u = 0; u < 4; ++u) {
      const f16x8* p = (const f16x8*)(Tbase + (size_t)u * N_);
      #pragma unroll
      for (int k = 0; k < 4; ++k) buf[u][k] = p[k * 512];
    }

    for (int tt0 = 0; tt0 < Tc; tt0 += 4) {
      #pragma unroll
      for (int u = 0; u < 4; ++u) {
        const int tt = tt0 + u;
        float a[8];
        #pragma unroll
        for (int cc = 0; cc < 8; ++cc) a[cc] = 0.f;
        #pragma unroll
        for (int k = 0; k < 4; ++k) {
          float si = s_sh[k * 32 + (t >> 4)];
          #pragma unroll
          for (int cc = 0; cc < 8; ++cc) a[cc] += si * (float)buf[u][k][cc];
        }
        if (tt + 4 < Tc) {
          const f16x8* p = (const f16x8*)(Tbase + (size_t)(tt + 4) * N_);
          #pragma unroll
          for (int k = 0; k < 4; ++k) buf[u][k] = p[k * 512];
        }
        #pragma unroll
        for (int cc = 0; cc < 8; ++cc) {
          a[cc] += __shfl_xor(a[cc], 16);
          a[cc] += __shfl_xor(a[cc], 32);
        }
        if (lane < 16) {
          #pragma unroll
          for (int cc = 0; cc < 8; ++cc) partv[w * 128 + lane * 8 + cc] = a[cc];
        }
        if (t < 128) {
          float ss = vprev * vprev;
          #pragma unroll
          for (int off = 32; off > 0; off >>= 1) ss += __shfl_xor(ss, off);
          if (lane == 0) red2[w] = ss;
        }
        ldsbar();
        if (t < 128) {
          float uj = 0.f;
          #pragma unroll
          for (int g = 0; g < 8; ++g) uj += partv[g * 128 + t];
          float v = fmaxf(uj, 0.f);
          float inv = 1.f / fmaxf(sqrtf(red2[0] + red2[1]), 1e-12f);
          if (tt > 0)
            out[((size_t)b * T_ + t0 + tt - 1) * D_ + t] = vprev * inv;
          s_sh[t] = v * inv;
          vprev = v;
        }
        ldsbar();
      }
    }

    if (t < 128) {
      float ss = vprev * vprev;
      #pragma unroll
      for (int off = 32; off > 0; off >>= 1) ss += __shfl_xor(ss, off);
      if (lane == 0) red2[w] = ss;
    }
    ldsbar();
    if (t < 128) {
      float inv = 1.f / fmaxf(sqrtf(red2[0] + red2[1]), 1e-12f);
      out[((size_t)b * T_ + t0 + Tc - 1) * D_ + t] = vprev * inv;
    }
  } else {
    // ======================= gemm block (chunk c+1) =========================
    const int g = c + 1;
    if (g >= nch) return;
    _Float16* trans = (g & 1) ? tbuf1 : tbuf0;
    const int t0g = g * Tc;
    const int gb = blockIdx.x - 32;
    const int bn = gb & 127;           // 128 n-blocks
    const int bm = gb >> 7;            // Tc/4 m-blocks

    _Float16* smA = (_Float16*)smem;            // 128x32 fp16 = 8 KB
    _Float16* smB = (_Float16*)(smem + 8192);   // 8 KB

    // staging: 512 chunks of 16B per tile; thread tid -> row tid>>2, kc tid&3
    const int rA = tid >> 2, kc = tid & 3;
    const int mc = bm * 128 + rA;
    const int bb = mc >> tcs;                   // mc / Tc
    const long grow = (long)bb * T_ + t0g + (mc & (Tc - 1));
    const _Float16* gA = h16 + grow * H_ + kc * 8;
    const _Float16* gB = w2t + (long)(bn * 128 + rA) * H_ + kc * 8;
    _Float16* lA = &smA[tid * 8];
    _Float16* lB = &smB[tid * 8];

    const int wm = w >> 1, wn = w & 1;          // 4x2 wave grid: 32m x 64n
    const int fm = lane & 15, fq = lane >> 4;

    f32x4 zero = {0.f, 0.f, 0.f, 0.f};
    f32x4 acc[2][4];
    #pragma unroll
    for (int i = 0; i < 2; ++i)
      #pragma unroll
      for (int j = 0; j < 4; ++j) acc[i][j] = zero;

    for (int kt = 0; kt < H_ / 32; ++kt) {
      __syncthreads();
      async_ld16(gA + kt * 32, lA);
      async_ld16(gB + kt * 32, lB);
      __syncthreads();
      f16x8 af[2], bf[4];
      #pragma unroll
      for (int mt = 0; mt < 2; ++mt)
        af[mt] = *(const f16x8*)&smA[(wm * 32 + mt * 16 + fm) * 32 + fq * 8];
      #pragma unroll
      for (int nt = 0; nt < 4; ++nt)
        bf[nt] = *(const f16x8*)&smB[(wn * 64 + nt * 16 + fm) * 32 + fq * 8];
      #pragma unroll
      for (int mt = 0; mt < 2; ++mt)
        #pragma unroll
        for (int nt = 0; nt < 4; ++nt)
          acc[mt][nt] = __builtin_amdgcn_mfma_f32_16x16x32_f16(af[mt], bf[nt], acc[mt][nt], 0, 0, 0);
    }

    // epilogue: C/D layout col=lane&15, row=(lane>>4)*4+r
    #pragma unroll
    for (int nt = 0; nt < 4; ++nt) {
      int col = bn * 128 + wn * 64 + nt * 16 + fm;
      float bias = b2[col];
      #pragma unroll
      for (int mt = 0; mt < 2; ++mt) {
        #pragma unroll
        for (int r = 0; r < 4; ++r) {
          long row = bm * 128 + wm * 32 + mt * 16 + fq * 4 + r;
          trans[row * (long)N_ + col] = (_Float16)(acc[mt][nt][r] + bias);
        }
      }
    }
  }
}

// ---------------------------------------------------------------------------
extern "C" void kernel_launch(void* const* d_in, const int* in_sizes, int n_in,
                              void* d_out, int out_size, void* d_ws, size_t ws_size,
                              hipStream_t stream) {
  const float* actions = (const float*)d_in[0];   // [32,512,64]
  const float* init_s  = (const float*)d_in[1];   // [128]
  const float* w1      = (const float*)d_in[2];   // [64,256]
  const float* b1      = (const float*)d_in[3];   // [256]
  const float* w2      = (const float*)d_in[4];   // [256,16384]
  const float* b2      = (const float*)d_in[5];   // [16384]
  float* out = (float*)d_out;                     // [32,512,128]

  uint8_t* ws = (uint8_t*)d_ws;
  _Float16* w2t = (_Float16*)ws;                          // 8 MB
  _Float16* h16 = (_Float16*)(ws + ((size_t)8 << 20));    // 8 MB
  const size_t trans_off = (size_t)16 << 20;

  // largest Tc whose DOUBLE-buffered trans fits: chunk bytes = Tc MiB
  int Tc = 16;
  const int cands[3] = {64, 32, 16};
  for (int i = 0; i < 3; ++i) {
    if (trans_off + 2 * ((size_t)cands[i] << 20) <= ws_size) { Tc = cands[i]; break; }
  }
  const int tcs = __builtin_ctz(Tc);
  _Float16* tbuf0 = (_Float16*)(ws + trans_off);
  _Float16* tbuf1 = (_Float16*)(ws + trans_off + ((size_t)Tc << 20));

  w2cast_kernel<<<dim3(N_ / 64, 4), 256, 0, stream>>>(w2, w2t);
  h_kernel<<<M_ / 32, 256, 0, stream>>>(actions, w1, b1, h16);

  const int nch = T_ / Tc;
  const int ngemm = 128 * (Tc / 4);   // (N/128) x (B*Tc/128)
  for (int c = -1; c < nch; ++c) {
    fused_kernel<<<32 + ngemm, 512, 0, stream>>>(
        h16, w2t, b2, tbuf0, tbuf1, init_s, out, Tc, tcs, c, nch);
  }
}

// Round 4
// 657.208 us; speedup vs baseline: 1.2839x; 1.0387x over previous
//
#include <hip/hip_runtime.h>
#include <stdint.h>
#include <math.h>

// ---------------------------------------------------------------------------
// PathIntegration: h = relu(actions@w1+b1); trans = (h@w2+b2) -> [B,T,D,D]
// s_{t+1} = l2norm(relu(s_t @ trans_t)); output ys[B,T,D] (f32)
// B=32 T=512 A=64 H=256 D=128
// Round 4: trans stored TRANSPOSED per step ([bt][j*128+i]) via a permuted
// w2t, so the rec matvec reads contiguous columns. Rec uses MFMA with
// s broadcast into all 16 A-rows, B-frags streamed global->VGPR with an
// 8-step ring (~32KB/wave in flight), one LDS barrier/step, deferred norm.
// >128 VGPR forces 1 block/CU: rec CUs are never shared with gemm blocks.
// ---------------------------------------------------------------------------

typedef _Float16 f16x8 __attribute__((ext_vector_type(8)));
typedef _Float16 f16x2 __attribute__((ext_vector_type(2)));
typedef float    f32x4 __attribute__((ext_vector_type(4)));

#define B_  32
#define T_  512
#define A_  64
#define H_  256
#define D_  128
#define N_  (D_ * D_)      // 16384
#define M_  (B_ * T_)      // 16384

__device__ inline void async_ld16(const void* g, void* l) {
  __builtin_amdgcn_global_load_lds(
      (__attribute__((address_space(1))) void*)g,
      (__attribute__((address_space(3))) void*)l, 16, 0, 0);
}

// ---------------- w2 cast + transpose + PERMUTE ------------------------------
// w2 [K=256][N=16384] f32 -> w2t [n'][K] fp16 with n' = (j<<7)|i for n=(i<<7)|j
// so the GEMM's column n' writes trans in [bt][j*128+i] (T^T) layout.
__global__ __launch_bounds__(256) void w2cast_kernel(const float* __restrict__ w2,
                                                     _Float16* __restrict__ w2t) {
  __shared__ float tile[64][65];
  const int t = threadIdx.x;
  const int n0 = blockIdx.x * 64, k0 = blockIdx.y * 64;
  const int nn = t & 63, kg = t >> 6;
  #pragma unroll
  for (int r = 0; r < 16; ++r) {
    int k = kg * 16 + r;
    tile[k][nn] = w2[(size_t)(k0 + k) * N_ + n0 + nn];
  }
  __syncthreads();
  const int kk = t & 63, ng = t >> 6;
  #pragma unroll
  for (int r = 0; r < 16; ++r) {
    int n = ng * 16 + r;
    int ngl = n0 + n;
    int nperm = ((ngl & 127) << 7) | (ngl >> 7);
    w2t[(size_t)nperm * H_ + k0 + kk] = (_Float16)tile[kk][n];
  }
}

// ---------------- h = relu(actions@w1+b1) fp16 [16384][256] ------------------
__global__ __launch_bounds__(256) void h_kernel(const float* __restrict__ actions,
                                                const float* __restrict__ w1,
                                                const float* __restrict__ b1,
                                                _Float16* __restrict__ h16) {
  __shared__ float w1s[32 * 256];
  __shared__ float acts[32 * 64];
  const int t = threadIdx.x;
  const size_t row0 = (size_t)blockIdx.x * 32;

  #pragma unroll
  for (int i = 0; i < 8; ++i) acts[t + i * 256] = actions[row0 * A_ + t + i * 256];

  float acc[32];
  float bj = b1[t];
  #pragma unroll
  for (int r = 0; r < 32; ++r) acc[r] = bj;

  for (int half = 0; half < 2; ++half) {
    __syncthreads();
    #pragma unroll
    for (int i = 0; i < 32; ++i) w1s[t + i * 256] = w1[half * 32 * 256 + t + i * 256];
    __syncthreads();
    #pragma unroll
    for (int r = 0; r < 32; ++r) {
      float a = acc[r];
      #pragma unroll
      for (int k = 0; k < 32; ++k)
        a += acts[r * 64 + half * 32 + k] * w1s[k * 256 + t];
      acc[r] = a;
    }
  }
  #pragma unroll
  for (int r = 0; r < 32; ++r)
    h16[(row0 + r) * H_ + t] = (_Float16)fmaxf(acc[r], 0.f);
}

// ---------------- fused: rec(chunk c) on blocks 0..31, gemm(chunk c+1) else --
__global__ __launch_bounds__(512, 2) void fused_kernel(
    const _Float16* __restrict__ h16, const _Float16* __restrict__ w2t,
    const float* __restrict__ b2, _Float16* __restrict__ tbuf0,
    _Float16* __restrict__ tbuf1, const float* __restrict__ init_s,
    float* __restrict__ out, int Tc, int tcs, int c, int nch) {

  __shared__ __align__(16) char smem[16896];
  const int tid  = threadIdx.x;
  const int lane = tid & 63;
  const int w    = tid >> 6;

  auto ldsbar = [&]() {
    asm volatile("s_waitcnt lgkmcnt(0)" ::: "memory");
    __builtin_amdgcn_s_barrier();
  };

  if (blockIdx.x < 32) {
    // ======================= recurrence block ===============================
    if (c < 0) return;
    const _Float16* trans = (c & 1) ? tbuf1 : tbuf0;
    const int b  = blockIdx.x;
    const int t0 = c * Tc;
    const int n16 = lane & 15, q = lane >> 4;
    const int col = w * 16 + n16;          // this lane's output column j

    _Float16* sb0 = (_Float16*)smem;          // 128 f16, parity 0
    _Float16* sb1 = (_Float16*)(smem + 256);  // parity 1
    float*    red2 = (float*)(smem + 512);    // [0],[1]

    // ---- init state (normalized carry) into sb0 ----
    float v0 = 0.f;
    if (tid < 128) {
      v0 = (t0 == 0) ? init_s[tid] : out[((size_t)b * T_ + t0 - 1) * D_ + tid];
      float ss = v0 * v0;
      #pragma unroll
      for (int off = 32; off > 0; off >>= 1) ss += __shfl_xor(ss, off);
      if (lane == 0) red2[w] = ss;
    }
    ldsbar();
    if (tid < 128) {
      float inv = 1.f / fmaxf(sqrtf(red2[0] + red2[1]), 1e-12f);
      sb0[tid] = (_Float16)(v0 * inv);
    }
    // ---- preload 8-step B-frag ring while init settles ----
    const _Float16* Bp = trans + (size_t)b * Tc * N_ + col * 128 + q * 8;
    f16x8 ring[8][4];
    #pragma unroll
    for (int u = 0; u < 8; ++u)
      #pragma unroll
      for (int f = 0; f < 4; ++f)
        ring[u][f] = *(const f16x8*)(Bp + (size_t)u * N_ + f * 32);
    ldsbar();

    const f32x4 zf = {0.f, 0.f, 0.f, 0.f};
    float uprev = 0.f;

    for (int tt0 = 0; tt0 < Tc; tt0 += 8) {
      #pragma unroll
      for (int u = 0; u < 8; ++u) {
        const int tt = tt0 + u;
        const _Float16* sbuf = (u & 1) ? sb1 : sb0;   // tt0 even -> tt&1 == u&1
        _Float16*       sout = (u & 1) ? sb0 : sb1;
        // A-frags: s broadcast into all 16 rows (addr independent of lane&15)
        f16x8 A[4];
        #pragma unroll
        for (int f = 0; f < 4; ++f)
          A[f] = *(const f16x8*)(sbuf + f * 32 + q * 8);
        // 4 independent MFMA over k-chunks; all C rows equal y[col]
        f32x4 cc[4];
        #pragma unroll
        for (int f = 0; f < 4; ++f)
          cc[f] = __builtin_amdgcn_mfma_f32_16x16x32_f16(A[f], ring[u][f], zf, 0, 0, 0);
        // ||s||^2 from the same A values (lane covers k={f*32+q*8+j})
        float ssp = 0.f;
        #pragma unroll
        for (int f = 0; f < 4; ++f) {
          const f16x2* ap = (const f16x2*)&A[f];
          #pragma unroll
          for (int p = 0; p < 4; ++p)
            ssp = __builtin_amdgcn_fdot2(ap[p], ap[p], ssp, false);
        }
        ssp += __shfl_xor(ssp, 16);
        ssp += __shfl_xor(ssp, 32);
        // prefetch step tt+8 into this slot
        if (tt + 8 < Tc) {
          #pragma unroll
          for (int f = 0; f < 4; ++f)
            ring[u][f] = *(const f16x8*)(Bp + (size_t)(tt + 8) * N_ + f * 32);
        }
        float inv = 1.f / fmaxf(sqrtf(ssp), 1e-12f);
        float y = cc[0][0] + cc[1][0] + cc[2][0] + cc[3][0];
        if (lane < 16 && tt > 0)
          out[((size_t)b * T_ + t0 + tt - 1) * D_ + col] = uprev * inv;
        float un = fmaxf(y, 0.f) * inv;   // = v_{t+1}/||v_t||, bounded
        uprev = un;
        if (lane < 16) sout[col] = (_Float16)un;
        ldsbar();
      }
    }

    // epilogue: norm of final stored state -> last output
    {
      const _Float16* sbuf = (Tc & 1) ? sb1 : sb0;
      f16x8 A[4];
      #pragma unroll
      for (int f = 0; f < 4; ++f)
        A[f] = *(const f16x8*)(sbuf + f * 32 + q * 8);
      float ssp = 0.f;
      #pragma unroll
      for (int f = 0; f < 4; ++f) {
        const f16x2* ap = (const f16x2*)&A[f];
        #pragma unroll
        for (int p = 0; p < 4; ++p)
          ssp = __builtin_amdgcn_fdot2(ap[p], ap[p], ssp, false);
      }
      ssp += __shfl_xor(ssp, 16);
      ssp += __shfl_xor(ssp, 32);
      float inv = 1.f / fmaxf(sqrtf(ssp), 1e-12f);
      if (lane < 16)
        out[((size_t)b * T_ + t0 + Tc - 1) * D_ + col] = uprev * inv;
    }
  } else {
    // ======================= gemm block (chunk c+1) =========================
    const int g = c + 1;
    if (g >= nch) return;
    _Float16* trans = (g & 1) ? tbuf1 : tbuf0;
    const int t0g = g * Tc;
    const int gb = blockIdx.x - 32;
    const int bn = gb & 127;           // 128 n'-blocks
    const int bm = gb >> 7;            // Tc/4 m-blocks

    _Float16* smA = (_Float16*)smem;            // 128x32 fp16 = 8 KB
    _Float16* smB = (_Float16*)(smem + 8192);   // 8 KB

    const int rA = tid >> 2, kc = tid & 3;
    const int mc = bm * 128 + rA;
    const int bb = mc >> tcs;                   // mc / Tc
    const long grow = (long)bb * T_ + t0g + (mc & (Tc - 1));
    const _Float16* gA = h16 + grow * H_ + kc * 8;
    const _Float16* gB = w2t + (long)(bn * 128 + rA) * H_ + kc * 8;
    _Float16* lA = &smA[tid * 8];
    _Float16* lB = &smB[tid * 8];

    const int wm = w >> 1, wn = w & 1;          // 4x2 wave grid: 32m x 64n
    const int fm = lane & 15, fq = lane >> 4;

    f32x4 zero = {0.f, 0.f, 0.f, 0.f};
    f32x4 acc[2][4];
    #pragma unroll
    for (int i = 0; i < 2; ++i)
      #pragma unroll
      for (int j = 0; j < 4; ++j) acc[i][j] = zero;

    for (int kt = 0; kt < H_ / 32; ++kt) {
      __syncthreads();
      async_ld16(gA + kt * 32, lA);
      async_ld16(gB + kt * 32, lB);
      __syncthreads();
      f16x8 af[2], bf[4];
      #pragma unroll
      for (int mt = 0; mt < 2; ++mt)
        af[mt] = *(const f16x8*)&smA[(wm * 32 + mt * 16 + fm) * 32 + fq * 8];
      #pragma unroll
      for (int nt = 0; nt < 4; ++nt)
        bf[nt] = *(const f16x8*)&smB[(wn * 64 + nt * 16 + fm) * 32 + fq * 8];
      #pragma unroll
      for (int mt = 0; mt < 2; ++mt)
        #pragma unroll
        for (int nt = 0; nt < 4; ++nt)
          acc[mt][nt] = __builtin_amdgcn_mfma_f32_16x16x32_f16(af[mt], bf[nt], acc[mt][nt], 0, 0, 0);
    }

    // epilogue: col here is the PERMUTED index n'=(j<<7)|i; bias needs orig n
    #pragma unroll
    for (int nt = 0; nt < 4; ++nt) {
      int col = bn * 128 + wn * 64 + nt * 16 + fm;
      int norig = ((col & 127) << 7) | (col >> 7);
      float bias = b2[norig];
      #pragma unroll
      for (int mt = 0; mt < 2; ++mt) {
        #pragma unroll
        for (int r = 0; r < 4; ++r) {
          long row = bm * 128 + wm * 32 + mt * 16 + fq * 4 + r;
          trans[row * (long)N_ + col] = (_Float16)(acc[mt][nt][r] + bias);
        }
      }
    }
  }
}

// ---------------------------------------------------------------------------
extern "C" void kernel_launch(void* const* d_in, const int* in_sizes, int n_in,
                              void* d_out, int out_size, void* d_ws, size_t ws_size,
                              hipStream_t stream) {
  const float* actions = (const float*)d_in[0];   // [32,512,64]
  const float* init_s  = (const float*)d_in[1];   // [128]
  const float* w1      = (const float*)d_in[2];   // [64,256]
  const float* b1      = (const float*)d_in[3];   // [256]
  const float* w2      = (const float*)d_in[4];   // [256,16384]
  const float* b2      = (const float*)d_in[5];   // [16384]
  float* out = (float*)d_out;                     // [32,512,128]

  uint8_t* ws = (uint8_t*)d_ws;
  _Float16* w2t = (_Float16*)ws;                          // 8 MB (permuted rows)
  _Float16* h16 = (_Float16*)(ws + ((size_t)8 << 20));    // 8 MB
  const size_t trans_off = (size_t)16 << 20;

  // largest Tc whose DOUBLE-buffered trans fits: chunk bytes = Tc MiB
  int Tc = 16;
  const int cands[3] = {64, 32, 16};
  for (int i = 0; i < 3; ++i) {
    if (trans_off + 2 * ((size_t)cands[i] << 20) <= ws_size) { Tc = cands[i]; break; }
  }
  const int tcs = __builtin_ctz(Tc);
  _Float16* tbuf0 = (_Float16*)(ws + trans_off);
  _Float16* tbuf1 = (_Float16*)(ws + trans_off + ((size_t)Tc << 20));

  w2cast_kernel<<<dim3(N_ / 64, 4), 256, 0, stream>>>(w2, w2t);
  h_kernel<<<M_ / 32, 256, 0, stream>>>(actions, w1, b1, h16);

  const int nch = T_ / Tc;
  const int ngemm = 128 * (Tc / 4);   // (N/128) x (B*Tc/128)
  for (int c = -1; c < nch; ++c) {
    fused_kernel<<<32 + ngemm, 512, 0, stream>>>(
        h16, w2t, b2, tbuf0, tbuf1, init_s, out, Tc, tcs, c, nch);
  }
}

// Round 5
// 656.963 us; speedup vs baseline: 1.2844x; 1.0004x over previous
//
#include <hip/hip_runtime.h>
#include <stdint.h>
#include <math.h>

// ---------------------------------------------------------------------------
// PathIntegration: h = relu(actions@w1+b1); trans = (h@w2+b2) -> [B,T,D,D]
// s_{t+1} = l2norm(relu(s_t @ trans_t)); output ys[B,T,D] (f32)
// B=32 T=512 A=64 H=256 D=128
// Round 5: rec prefetch ring pinned with inline-asm global_load_dwordx4 +
// explicit vmcnt schedule (compiler collapsed the C++ ring: VGPR was 84).
// Ring liveness forces VGPR>128 -> 1 block/CU: rec CUs isolated from gemm.
// out stores batched via LDS, flushed per 8 steps. GEMM persistent on the
// remaining 224 blocks. trans double-buffered, [bt][j*128+i] layout.
// ---------------------------------------------------------------------------

typedef _Float16 f16x8 __attribute__((ext_vector_type(8)));
typedef _Float16 f16x2 __attribute__((ext_vector_type(2)));
typedef float    f32x4 __attribute__((ext_vector_type(4)));

#define B_  32
#define T_  512
#define A_  64
#define H_  256
#define D_  128
#define N_  (D_ * D_)      // 16384
#define M_  (B_ * T_)      // 16384

__device__ inline void async_ld16(const void* g, void* l) {
  __builtin_amdgcn_global_load_lds(
      (__attribute__((address_space(1))) void*)g,
      (__attribute__((address_space(3))) void*)l, 16, 0, 0);
}

// 4 pinned 16B loads: slot[0..3] <- p + {0,64,128,192} bytes
#define LD4(SLOT, P)                                                         \
  asm volatile("global_load_dwordx4 %0, %4, off\n\t"                         \
               "global_load_dwordx4 %1, %4, off offset:64\n\t"               \
               "global_load_dwordx4 %2, %4, off offset:128\n\t"              \
               "global_load_dwordx4 %3, %4, off offset:192"                  \
               : "=v"((SLOT)[0]), "=v"((SLOT)[1]), "=v"((SLOT)[2]),          \
                 "=v"((SLOT)[3])                                             \
               : "v"(P) : "memory")

// wait until slot's 4 loads (issued 8 steps ago) are done; tie regs for dep
#define RWAIT(SLOT, WAITN)                                                   \
  asm volatile("s_waitcnt vmcnt(" #WAITN ")"                                 \
               : "+v"((SLOT)[0]), "+v"((SLOT)[1]), "+v"((SLOT)[2]),          \
                 "+v"((SLOT)[3]) :: "memory")

// ---------------- w2 cast + transpose + PERMUTE ------------------------------
// w2 [K=256][N=16384] f32 -> w2t [n'][K] fp16 with n' = (j<<7)|i for n=(i<<7)|j
__global__ __launch_bounds__(256) void w2cast_kernel(const float* __restrict__ w2,
                                                     _Float16* __restrict__ w2t) {
  __shared__ float tile[64][65];
  const int t = threadIdx.x;
  const int n0 = blockIdx.x * 64, k0 = blockIdx.y * 64;
  const int nn = t & 63, kg = t >> 6;
  #pragma unroll
  for (int r = 0; r < 16; ++r) {
    int k = kg * 16 + r;
    tile[k][nn] = w2[(size_t)(k0 + k) * N_ + n0 + nn];
  }
  __syncthreads();
  const int kk = t & 63, ng = t >> 6;
  #pragma unroll
  for (int r = 0; r < 16; ++r) {
    int n = ng * 16 + r;
    int ngl = n0 + n;
    int nperm = ((ngl & 127) << 7) | (ngl >> 7);
    w2t[(size_t)nperm * H_ + k0 + kk] = (_Float16)tile[kk][n];
  }
}

// ---------------- h = relu(actions@w1+b1) fp16 [16384][256] ------------------
__global__ __launch_bounds__(256) void h_kernel(const float* __restrict__ actions,
                                                const float* __restrict__ w1,
                                                const float* __restrict__ b1,
                                                _Float16* __restrict__ h16) {
  __shared__ float w1s[32 * 256];
  __shared__ float acts[32 * 64];
  const int t = threadIdx.x;
  const size_t row0 = (size_t)blockIdx.x * 32;

  #pragma unroll
  for (int i = 0; i < 8; ++i) acts[t + i * 256] = actions[row0 * A_ + t + i * 256];

  float acc[32];
  float bj = b1[t];
  #pragma unroll
  for (int r = 0; r < 32; ++r) acc[r] = bj;

  for (int half = 0; half < 2; ++half) {
    __syncthreads();
    #pragma unroll
    for (int i = 0; i < 32; ++i) w1s[t + i * 256] = w1[half * 32 * 256 + t + i * 256];
    __syncthreads();
    #pragma unroll
    for (int r = 0; r < 32; ++r) {
      float a = acc[r];
      #pragma unroll
      for (int k = 0; k < 32; ++k)
        a += acts[r * 64 + half * 32 + k] * w1s[k * 256 + t];
      acc[r] = a;
    }
  }
  #pragma unroll
  for (int r = 0; r < 32; ++r)
    h16[(row0 + r) * H_ + t] = (_Float16)fmaxf(acc[r], 0.f);
}

// ---------------- fused: rec(chunk c) blocks 0..31, persistent gemm else ----
__global__ __launch_bounds__(512, 2) void fused_kernel(
    const _Float16* __restrict__ h16, const _Float16* __restrict__ w2t,
    const float* __restrict__ b2, _Float16* __restrict__ tbuf0,
    _Float16* __restrict__ tbuf1, const float* __restrict__ init_s,
    float* __restrict__ out, int Tc, int tcs, int c, int nch) {

  __shared__ __align__(16) char smem[16896];
  const int tid  = threadIdx.x;
  const int lane = tid & 63;
  const int w    = tid >> 6;

  auto ldsbar = [&]() {
    asm volatile("s_waitcnt lgkmcnt(0)" ::: "memory");
    __builtin_amdgcn_s_barrier();
  };

  if (blockIdx.x < 32) {
    // ======================= recurrence block ===============================
    if (c < 0) return;
    const _Float16* trans = (c & 1) ? tbuf1 : tbuf0;
    const int b  = blockIdx.x;
    const int t0 = c * Tc;
    const int n16 = lane & 15, q = lane >> 4;
    const int col = w * 16 + n16;          // this lane's output column j

    _Float16* sb0  = (_Float16*)smem;          // 128 f16
    _Float16* sb1  = (_Float16*)(smem + 256);
    float*    red2 = (float*)(smem + 512);     // [0],[1]
    float*    osh  = (float*)(smem + 1024);    // [8][128] f32 out staging

    // ---- init state (normalized carry) into sb0 ----
    float v0 = 0.f;
    if (tid < 128) {
      v0 = (t0 == 0) ? init_s[tid] : out[((size_t)b * T_ + t0 - 1) * D_ + tid];
      float ss = v0 * v0;
      #pragma unroll
      for (int off = 32; off > 0; off >>= 1) ss += __shfl_xor(ss, off);
      if (lane == 0) red2[w] = ss;
    }
    ldsbar();
    if (tid < 128) {
      float inv = 1.f / fmaxf(sqrtf(red2[0] + red2[1]), 1e-12f);
      sb0[tid] = (_Float16)(v0 * inv);
    }

    const _Float16* Bp = trans + (size_t)b * Tc * N_ + col * 128 + q * 8;
    f16x8 ring[8][4];
    LD4(ring[0], Bp + 0 * (size_t)N_);
    LD4(ring[1], Bp + 1 * (size_t)N_);
    LD4(ring[2], Bp + 2 * (size_t)N_);
    LD4(ring[3], Bp + 3 * (size_t)N_);
    LD4(ring[4], Bp + 4 * (size_t)N_);
    LD4(ring[5], Bp + 5 * (size_t)N_);
    LD4(ring[6], Bp + 6 * (size_t)N_);
    LD4(ring[7], Bp + 7 * (size_t)N_);
    ldsbar();

    const f32x4 zf = {0.f, 0.f, 0.f, 0.f};
    const _Float16* pf = Bp + 8 * (size_t)N_;
    float uprev = 0.f;

#define RSTEP(U, WAITN, DO_PF)                                               \
    {                                                                        \
      RWAIT(ring[U], WAITN);                                                 \
      const _Float16* sbuf = ((U) & 1) ? sb1 : sb0;                          \
      _Float16*       sout = ((U) & 1) ? sb0 : sb1;                          \
      f16x8 Af0 = *(const f16x8*)(sbuf + 0 * 32 + q * 8);                    \
      f16x8 Af1 = *(const f16x8*)(sbuf + 1 * 32 + q * 8);                    \
      f16x8 Af2 = *(const f16x8*)(sbuf + 2 * 32 + q * 8);                    \
      f16x8 Af3 = *(const f16x8*)(sbuf + 3 * 32 + q * 8);                    \
      f32x4 c0 = __builtin_amdgcn_mfma_f32_16x16x32_f16(Af0, ring[U][0], zf, 0, 0, 0); \
      f32x4 c1 = __builtin_amdgcn_mfma_f32_16x16x32_f16(Af1, ring[U][1], zf, 0, 0, 0); \
      f32x4 c2 = __builtin_amdgcn_mfma_f32_16x16x32_f16(Af2, ring[U][2], zf, 0, 0, 0); \
      f32x4 c3 = __builtin_amdgcn_mfma_f32_16x16x32_f16(Af3, ring[U][3], zf, 0, 0, 0); \
      const f16x2* a0 = (const f16x2*)&Af0;                                  \
      const f16x2* a1 = (const f16x2*)&Af1;                                  \
      const f16x2* a2 = (const f16x2*)&Af2;                                  \
      const f16x2* a3 = (const f16x2*)&Af3;                                  \
      float sA = __builtin_amdgcn_fdot2(a0[0], a0[0], 0.f, false);           \
      float sB = __builtin_amdgcn_fdot2(a1[0], a1[0], 0.f, false);           \
      float sC = __builtin_amdgcn_fdot2(a2[0], a2[0], 0.f, false);           \
      float sD = __builtin_amdgcn_fdot2(a3[0], a3[0], 0.f, false);           \
      sA = __builtin_amdgcn_fdot2(a0[1], a0[1], sA, false);                  \
      sB = __builtin_amdgcn_fdot2(a1[1], a1[1], sB, false);                  \
      sC = __builtin_amdgcn_fdot2(a2[1], a2[1], sC, false);                  \
      sD = __builtin_amdgcn_fdot2(a3[1], a3[1], sD, false);                  \
      sA = __builtin_amdgcn_fdot2(a0[2], a0[2], sA, false);                  \
      sB = __builtin_amdgcn_fdot2(a1[2], a1[2], sB, false);                  \
      sC = __builtin_amdgcn_fdot2(a2[2], a2[2], sC, false);                  \
      sD = __builtin_amdgcn_fdot2(a3[2], a3[2], sD, false);                  \
      sA = __builtin_amdgcn_fdot2(a0[3], a0[3], sA, false);                  \
      sB = __builtin_amdgcn_fdot2(a1[3], a1[3], sB, false);                  \
      sC = __builtin_amdgcn_fdot2(a2[3], a2[3], sC, false);                  \
      sD = __builtin_amdgcn_fdot2(a3[3], a3[3], sD, false);                  \
      if (DO_PF) { LD4(ring[U], pf); pf += N_; }                             \
      float ssp = (sA + sB) + (sC + sD);                                     \
      ssp += __shfl_xor(ssp, 16);                                            \
      ssp += __shfl_xor(ssp, 32);                                            \
      float inv = 1.f / fmaxf(sqrtf(ssp), 1e-12f);                           \
      float y = c0[0] + c1[0] + c2[0] + c3[0];                               \
      float un = fmaxf(y, 0.f) * inv;                                        \
      if (lane < 16) {                                                       \
        osh[(((U) + 7) & 7) * 128 + col] = uprev * inv;                      \
        sout[col] = (_Float16)un;                                            \
      }                                                                      \
      uprev = un;                                                            \
      ldsbar();                                                              \
    }

    // flush 8 staged out rows (steps base-1 .. base+6)
    auto flush = [&](int base) {
      const int r = tid >> 6, cj = (lane) * 2;
      float2 o = *(const float2*)&osh[r * 128 + cj];
      int gs = (r == 7) ? base - 1 : base + r;
      ldsbar();
      if (gs >= 0) {
        float* gp = out + ((size_t)b * T_ + t0 + gs) * D_ + cj;
        asm volatile("global_store_dwordx2 %0, %1, off" :: "v"(gp), "v"(o) : "memory");
      }
    };

    int tt0 = 0;
    for (; tt0 + 16 <= Tc; tt0 += 8) {
      RSTEP(0, 28, 1) RSTEP(1, 28, 1) RSTEP(2, 28, 1) RSTEP(3, 28, 1)
      RSTEP(4, 28, 1) RSTEP(5, 28, 1) RSTEP(6, 28, 1) RSTEP(7, 28, 1)
      flush(tt0);
    }
    // tail group: drain schedule
    RSTEP(0, 28, 0) RSTEP(1, 24, 0) RSTEP(2, 20, 0) RSTEP(3, 16, 0)
    RSTEP(4, 12, 0) RSTEP(5,  8, 0) RSTEP(6,  4, 0) RSTEP(7,  0, 0)
    flush(Tc - 8);

    // epilogue: final norm of sb0 (state after step Tc-1), write step Tc-1
    {
      float ss = 0.f;
      if (tid < 128) {
        float x = (float)sb0[tid];
        ss = x * x;
        #pragma unroll
        for (int off = 32; off > 0; off >>= 1) ss += __shfl_xor(ss, off);
        if (lane == 0) red2[w] = ss;
      }
      ldsbar();
      float inv = 1.f / fmaxf(sqrtf(red2[0] + red2[1]), 1e-12f);
      if (lane < 16) {
        float* gp = out + ((size_t)b * T_ + t0 + Tc - 1) * D_ + col;
        float o = uprev * inv;
        asm volatile("global_store_dword %0, %1, off" :: "v"(gp), "v"(o) : "memory");
      }
      asm volatile("s_waitcnt vmcnt(0)" ::: "memory");
    }
#undef RSTEP
  } else {
    // ======================= persistent gemm (chunk c+1) ====================
    const int g = c + 1;
    if (g >= nch) return;
    _Float16* trans = (g & 1) ? tbuf1 : tbuf0;
    const int t0g = g * Tc;

    _Float16* smA = (_Float16*)smem;            // 128x32 fp16 = 8 KB
    _Float16* smB = (_Float16*)(smem + 8192);   // 8 KB

    const int rA = tid >> 2, kc = tid & 3;
    const int wm = w >> 1, wn = w & 1;          // 4x2 wave grid: 32m x 64n
    const int fm = lane & 15, fq = lane >> 4;
    const f32x4 zero = {0.f, 0.f, 0.f, 0.f};

    const int ntiles = 32 * Tc;                 // (B*Tc/128) * (N/128)
    for (int tile = (int)blockIdx.x - 32; tile < ntiles; tile += 224) {
      const int bn = tile & 127;
      const int bm = tile >> 7;

      const int mc = bm * 128 + rA;
      const int bb = mc >> tcs;                 // mc / Tc
      const long grow = (long)bb * T_ + t0g + (mc & (Tc - 1));
      const _Float16* gA = h16 + grow * H_ + kc * 8;
      const _Float16* gB = w2t + (long)(bn * 128 + rA) * H_ + kc * 8;
      _Float16* lA = &smA[tid * 8];
      _Float16* lB = &smB[tid * 8];

      f32x4 acc[2][4];
      #pragma unroll
      for (int i = 0; i < 2; ++i)
        #pragma unroll
        for (int j = 0; j < 4; ++j) acc[i][j] = zero;

      for (int kt = 0; kt < H_ / 32; ++kt) {
        __syncthreads();
        async_ld16(gA + kt * 32, lA);
        async_ld16(gB + kt * 32, lB);
        __syncthreads();
        f16x8 af[2], bf[4];
        #pragma unroll
        for (int mt = 0; mt < 2; ++mt)
          af[mt] = *(const f16x8*)&smA[(wm * 32 + mt * 16 + fm) * 32 + fq * 8];
        #pragma unroll
        for (int nt = 0; nt < 4; ++nt)
          bf[nt] = *(const f16x8*)&smB[(wn * 64 + nt * 16 + fm) * 32 + fq * 8];
        #pragma unroll
        for (int mt = 0; mt < 2; ++mt)
          #pragma unroll
          for (int nt = 0; nt < 4; ++nt)
            acc[mt][nt] = __builtin_amdgcn_mfma_f32_16x16x32_f16(af[mt], bf[nt], acc[mt][nt], 0, 0, 0);
      }

      // epilogue: col is PERMUTED n'=(j<<7)|i; bias needs orig n
      #pragma unroll
      for (int nt = 0; nt < 4; ++nt) {
        int col = bn * 128 + wn * 64 + nt * 16 + fm;
        int norig = ((col & 127) << 7) | (col >> 7);
        float bias = b2[norig];
        #pragma unroll
        for (int mt = 0; mt < 2; ++mt) {
          #pragma unroll
          for (int r = 0; r < 4; ++r) {
            long row = bm * 128 + wm * 32 + mt * 16 + fq * 4 + r;
            trans[row * (long)N_ + col] = (_Float16)(acc[mt][nt][r] + bias);
          }
        }
      }
      __syncthreads();
    }
  }
}

// ---------------------------------------------------------------------------
extern "C" void kernel_launch(void* const* d_in, const int* in_sizes, int n_in,
                              void* d_out, int out_size, void* d_ws, size_t ws_size,
                              hipStream_t stream) {
  const float* actions = (const float*)d_in[0];   // [32,512,64]
  const float* init_s  = (const float*)d_in[1];   // [128]
  const float* w1      = (const float*)d_in[2];   // [64,256]
  const float* b1      = (const float*)d_in[3];   // [256]
  const float* w2      = (const float*)d_in[4];   // [256,16384]
  const float* b2      = (const float*)d_in[5];   // [16384]
  float* out = (float*)d_out;                     // [32,512,128]

  uint8_t* ws = (uint8_t*)d_ws;
  _Float16* w2t = (_Float16*)ws;                          // 8 MB (permuted rows)
  _Float16* h16 = (_Float16*)(ws + ((size_t)8 << 20));    // 8 MB
  const size_t trans_off = (size_t)16 << 20;

  // largest Tc (multiple of 8, >=16) whose double-buffered trans fits
  int Tc = 16;
  const int cands[3] = {64, 32, 16};
  for (int i = 0; i < 3; ++i) {
    if (trans_off + 2 * ((size_t)cands[i] << 20) <= ws_size) { Tc = cands[i]; break; }
  }
  const int tcs = __builtin_ctz(Tc);
  _Float16* tbuf0 = (_Float16*)(ws + trans_off);
  _Float16* tbuf1 = (_Float16*)(ws + trans_off + ((size_t)Tc << 20));

  w2cast_kernel<<<dim3(N_ / 64, 4), 256, 0, stream>>>(w2, w2t);
  h_kernel<<<M_ / 32, 256, 0, stream>>>(actions, w1, b1, h16);

  const int nch = T_ / Tc;
  for (int c = -1; c < nch; ++c) {
    fused_kernel<<<256, 512, 0, stream>>>(
        h16, w2t, b2, tbuf0, tbuf1, init_s, out, Tc, tcs, c, nch);
  }
}